// Round 10
// baseline (148.808 us; speedup 1.0000x reference)
//
#include <hip/hip_runtime.h>
#include <math.h>
#include <stdint.h>

#define N_NODES   50000
#define EMBED_DIM 320
#define N_EDGES   400000
#define HID       64

typedef __bf16 bf16x8 __attribute__((ext_vector_type(8)));
typedef float  f32x4  __attribute__((ext_vector_type(4)));

// direct-to-LDS DMA, 16B per lane (result-less -> compiler cannot sink it).
__device__ __forceinline__ void async_copy16(void* lds_dst, const void* g_src) {
    __builtin_amdgcn_global_load_lds(
        (const __attribute__((address_space(1))) uint32_t*)g_src,
        (__attribute__((address_space(3))) uint32_t*)lds_dst,
        16, 0, 0);
}

// ---------------------------------------------------------------------------
// prep_b: blocks 0..19 repack W1 -> Bg (MFMA B-fragment order, bf16);
//         block 20 computes cterm = b1 + embed[nid] @ W1[640:960] (fp32).
//   Bg[((s*8+f)*64 + l)*8 + j] = (bf16) B[32s + 8*(l>>4) + j][16f + (l&15)]
//   where B[k][c] = W1[k + (c>=64)*320][c&63]
// ---------------------------------------------------------------------------
__global__ __launch_bounds__(256) void prep_b(const float* __restrict__ W1,
                                              const float* __restrict__ b1,
                                              const int* __restrict__ node_id,
                                              const float* __restrict__ E,
                                              __bf16* __restrict__ Bg,
                                              float* __restrict__ cterm_g) {
    if (blockIdx.x < 20) {
        int chunk = blockIdx.x * 256 + threadIdx.x;   // < 5120
        int l  = chunk & 63;
        int sf = chunk >> 6;
        int f  = sf & 7, s = sf >> 3;
        int c  = f * 16 + (l & 15);
        int k0 = s * 32 + (l >> 4) * 8;
        const float* src = W1 + ((size_t)k0 + (c >= 64 ? EMBED_DIM : 0)) * HID + (c & 63);
        __bf16* dst = Bg + (size_t)chunk * 8;
        #pragma unroll
        for (int j = 0; j < 8; ++j) dst[j] = (__bf16)src[(size_t)j * HID];
    } else {
        __shared__ float red[4][64];
        const int tid = threadIdx.x;
        const int j = tid & 63;
        const int g = tid >> 6;
        const int nid = node_id[0];
        const float* erow = E + (size_t)nid * EMBED_DIM;
        float s = 0.f;
        #pragma unroll 4
        for (int k = g * 80; k < (g + 1) * 80; ++k)
            s = fmaf(erow[k], W1[(size_t)(2 * EMBED_DIM + k) * HID + j], s);
        red[g][j] = s;
        __syncthreads();
        if (tid < 64)
            cterm_g[tid] = b1[tid] + red[0][tid] + red[1][tid] + red[2][tid] + red[3][tid];
    }
}

// ---------------------------------------------------------------------------
// node_gemm (MFMA): P[n][0:64]   = embed[n] @ W1[0:320]   + cterm   (bf16 out)
//                   P[n][64:128] = embed[n] @ W1[320:640]
// R9 structure -- two streams on two COUNTERS so no full drain ever happens:
//   B (frag table, 80 KB, same for all blocks): global_load_lds -> sB, issued
//     FIRST; in-loop B reads are ds_read (lgkmcnt), decoupled from vmcnt.
//   A (this block's 64 rows): 20x dwordx4 -> REGISTERS, issued second, pinned
//     by sched_barrier(0) (R6: unpinned version was silently sunk). Step s's
//     A-use gets a compiler-inserted progressive vmcnt -- loads stay in
//     flight across the whole MFMA loop. One manual vmcnt(20) (B-DMA = the
//     oldest 20 issues, always complete at <=20 outstanding) + one barrier.
// __launch_bounds__(256,2): VGPR headroom for the 80-reg A buffer; LDS 80 KB
// -> 2 blocks/CU, 8 waves x 20 KB = 160 KB/CU in flight, issued continuously.
// Tripwire: VGPR_Count <= 96 in the trace => the A buffer was sunk again.
// ---------------------------------------------------------------------------
__global__ __launch_bounds__(256, 2) void node_gemm(const float* __restrict__ E,
                                                    const __bf16* __restrict__ Bg,
                                                    const float* __restrict__ cterm_g,
                                                    __bf16* __restrict__ P) {
    __shared__ __bf16 sB[5120 * 8];   // 80 KB, whole fragment table

    const int tid  = threadIdx.x;
    const int wave = tid >> 6;
    const int lane = tid & 63;
    const int r16  = lane & 15;    // A row within wave tile / C col
    const int kg   = lane >> 4;    // k-group / C row-group
    const int m0   = blockIdx.x * 64;
    const int m0w  = m0 + wave * 16;

    // ---- 1) DMA the whole B table to LDS (oldest 20 vmem issues) ----
    #pragma unroll
    for (int it = 0; it < 20; ++it) {
        int g = it * 256 + tid;        // 16B chunk id, 0..5119
        async_copy16((char*)sB + (size_t)g * 16, (const char*)Bg + (size_t)g * 16);
    }
    __builtin_amdgcn_sched_barrier(0);   // B-DMA stays the oldest block of issues

    // ---- 2) cterm + the full A stream into registers ----
    float ct[4];
    #pragma unroll
    for (int fi = 0; fi < 4; ++fi) ct[fi] = cterm_g[fi * 16 + r16];

    int arow_i = m0w + r16;
    if (arow_i > N_NODES - 1) arow_i = N_NODES - 1;   // dup row; never stored
    const float* arow = E + (size_t)arow_i * EMBED_DIM + kg * 8;

    float4 aA[10][2];
    #pragma unroll
    for (int s = 0; s < 10; ++s) {
        aA[s][0] = *(const float4*)(arow + s * 32 + 0);
        aA[s][1] = *(const float4*)(arow + s * 32 + 4);
    }
    __builtin_amdgcn_sched_barrier(0);   // pin the loads: nothing moves across

    // wait only for B (outstanding <= 20 => the oldest >=24 issues -- all
    // B-DMA + ct in any order -- are complete; the A stream keeps flying)
    asm volatile("s_waitcnt vmcnt(20)" ::: "memory");
    __builtin_amdgcn_sched_barrier(0);   // rule #18: fence after asm waitcnt
    __builtin_amdgcn_s_barrier();        // all waves' B chunks in sB

    // ---- 3) MFMA loop: A from regs (progressive vmcnt), B via ds_read ----
    const __bf16* bb = sB + (size_t)lane * 8;
    f32x4 acc[8] = {};
    #pragma unroll
    for (int s = 0; s < 10; ++s) {
        bf16x8 av;
        av[0] = (__bf16)aA[s][0].x; av[1] = (__bf16)aA[s][0].y;
        av[2] = (__bf16)aA[s][0].z; av[3] = (__bf16)aA[s][0].w;
        av[4] = (__bf16)aA[s][1].x; av[5] = (__bf16)aA[s][1].y;
        av[6] = (__bf16)aA[s][1].z; av[7] = (__bf16)aA[s][1].w;
        #pragma unroll
        for (int f = 0; f < 8; ++f) {
            bf16x8 bv = *(const bf16x8*)(bb + (size_t)(s * 8 + f) * 512);
            acc[f] = __builtin_amdgcn_mfma_f32_16x16x32_bf16(av, bv, acc[f], 0, 0, 0);
        }
    }

    // ---- 4) epilogue: C/D layout col=lane&15, row=(lane>>4)*4+j ----
    #pragma unroll
    for (int f = 0; f < 8; ++f) {
        float c = (f < 4) ? ct[f] : 0.f;
        #pragma unroll
        for (int j = 0; j < 4; ++j) {
            int gr = m0w + kg * 4 + j;
            if (gr < N_NODES)
                P[(size_t)gr * 128 + f * 16 + r16] = (__bf16)(acc[f][j] + c);
        }
    }
}

// ---------------------------------------------------------------------------
// edge_kernel: 8 lanes/edge, one bf16x8 (16B) per operand per lane.
// h = relu(P[col][0:64] + P[row][64:128]); w = h.W2 + b2   (cterm is in P)
// gate = (log(e) - log1p(-e) + w)/tmp ; out = sigmoid(gate)
// ---------------------------------------------------------------------------
__global__ __launch_bounds__(256) void edge_kernel(const int* __restrict__ eidx,
                                                   const float* __restrict__ eps,
                                                   const __bf16* __restrict__ P,
                                                   const float* __restrict__ W2,
                                                   const float* __restrict__ b2,
                                                   const float* __restrict__ tmp,
                                                   float* __restrict__ out) {
    const int gid = blockIdx.x * blockDim.x + threadIdx.x;
    const int e   = gid >> 3;          // edge id
    const int q   = gid & 7;           // lane within edge group
    if (e >= N_EDGES) return;

    int col = eidx[e];
    int row = eidx[N_EDGES + e];
    col = min(max(col, 0), N_NODES - 1);
    row = min(max(row, 0), N_NODES - 1);

    bf16x8 a = *(const bf16x8*)(P + (size_t)col * 128 + q * 8);
    bf16x8 c = *(const bf16x8*)(P + (size_t)row * 128 + 64 + q * 8);
    float4 w0 = *(const float4*)(W2 + q * 8);
    float4 w1 = *(const float4*)(W2 + q * 8 + 4);

    float s = 0.f;
    s = fmaf(fmaxf((float)a[0] + (float)c[0], 0.f), w0.x, s);
    s = fmaf(fmaxf((float)a[1] + (float)c[1], 0.f), w0.y, s);
    s = fmaf(fmaxf((float)a[2] + (float)c[2], 0.f), w0.z, s);
    s = fmaf(fmaxf((float)a[3] + (float)c[3], 0.f), w0.w, s);
    s = fmaf(fmaxf((float)a[4] + (float)c[4], 0.f), w1.x, s);
    s = fmaf(fmaxf((float)a[5] + (float)c[5], 0.f), w1.y, s);
    s = fmaf(fmaxf((float)a[6] + (float)c[6], 0.f), w1.z, s);
    s = fmaf(fmaxf((float)a[7] + (float)c[7], 0.f), w1.w, s);

    s += __shfl_xor(s, 1);
    s += __shfl_xor(s, 2);
    s += __shfl_xor(s, 4);

    if (q == 0) {
        float w  = s + b2[0];
        const float bias = 0.0001f;               // SAMPLE_BIAS + 1e-4
        float ee = eps[e] * (1.0f - 2.0f * bias) + bias;
        float gate = (logf(ee) - log1pf(-ee) + w) / tmp[0];
        out[e] = 1.0f / (1.0f + expf(-gate));
    }
}

// ---------------------------------------------------------------------------
extern "C" void kernel_launch(void* const* d_in, const int* in_sizes, int n_in,
                              void* d_out, int out_size, void* d_ws, size_t ws_size,
                              hipStream_t stream) {
    // inputs: x, embed, edge_index, node_id, tmp, eps, W1, b1, W2, b2
    const float* embed = (const float*)d_in[1];
    const int*   eidx  = (const int*)d_in[2];
    const int*   nid   = (const int*)d_in[3];
    const float* tmp   = (const float*)d_in[4];
    const float* eps   = (const float*)d_in[5];
    const float* W1    = (const float*)d_in[6];
    const float* b1    = (const float*)d_in[7];
    const float* W2    = (const float*)d_in[8];
    const float* b2    = (const float*)d_in[9];
    float*       out   = (float*)d_out;

    // workspace: P[50000*128] bf16 (12.8 MB) | Bg[5120*8] bf16 (80 KB) | cterm[64] f32
    __bf16* P       = (__bf16*)d_ws;
    __bf16* Bg      = (__bf16*)((char*)d_ws + (size_t)N_NODES * 128 * sizeof(__bf16));
    float*  cterm_g = (float*)((char*)Bg + (size_t)5120 * 8 * sizeof(__bf16));

    prep_b<<<21, 256, 0, stream>>>(W1, b1, nid, embed, Bg, cterm_g);

    int gemm_blocks = (N_NODES + 63) / 64;        // 782
    node_gemm<<<gemm_blocks, 256, 0, stream>>>(embed, Bg, cterm_g, P);

    int edge_threads = N_EDGES * 8;               // 3.2M
    edge_kernel<<<(edge_threads + 255) / 256, 256, 0, stream>>>(
        eidx, eps, P, W2, b2, tmp, out);
}